// Round 6
// baseline (112.651 us; speedup 1.0000x reference)
//
#include <hip/hip_runtime.h>
#include <hip/hip_bf16.h>

#define ETA_C  0.1f
#define BETA_C 0.05f
#define MU_C   0.05f
#define MINI_C 1e-6f

typedef __attribute__((ext_vector_type(8))) short short8;
typedef __attribute__((ext_vector_type(4))) float f32x4;

// ---------- DPP wave-64 sum ----------
template<int CTRL, int ROWMASK>
__device__ __forceinline__ float dpp_add(float x) {
  int v = __builtin_amdgcn_update_dpp(0, __float_as_int(x), CTRL, ROWMASK, 0xf, true);
  return x + __int_as_float(v);
}

__device__ __forceinline__ float wave_sum(float x) {
  x = dpp_add<0xB1,  0xF>(x);
  x = dpp_add<0x4E,  0xF>(x);
  x = dpp_add<0x141, 0xF>(x);
  x = dpp_add<0x140, 0xF>(x);
  x = dpp_add<0x142, 0xA>(x);
  x = dpp_add<0x143, 0xC>(x);
  return __int_as_float(__builtin_amdgcn_readlane(__float_as_int(x), 63));
}

__device__ __forceinline__ float rl(float x, int k) {
  return __int_as_float(__builtin_amdgcn_readlane(__float_as_int(x), k));
}

__device__ __forceinline__ short bf16r(float x) {
  unsigned u = __float_as_uint(x);
  u += 0x7fffu + ((u >> 16) & 1u);
  return (short)(u >> 16);
}

__device__ __forceinline__ float bf2f(short s) {
  return __uint_as_float(((unsigned)(unsigned short)s) << 16);
}

// ---------- LDS XOR swizzle for 64-short (128B) rows ----------
// Column-slice reads of row-major [*][64] bf16 tiles are 16-way bank
// conflicts (row stride 128B == 32 banks). XOR the 16B slot with (row&7):
// reads (short8) drop to 2-way (free), column writes to <=8-way.
// R4->R5: SQ_LDS_BANK_CONFLICT 3.0M -> gone, -2 us.
__device__ __forceinline__ int swz(int row, int col) {
  return (row << 6) + ((col & 7) | ((((col >> 3) ^ row) & 7) << 3));
}
__device__ __forceinline__ int swz8(int row, int slot) {   // 16B-aligned slot
  return (row << 6) + (((slot ^ row) & 7) << 3);
}

// ---------- kernel A: per-block column-sum partials + zero atomic dests ----
// 256 blocks (1/CU): full-chip streaming of the 7.7 MB cold input.
// part written COLUMN-major (part[col*256 + bx]) so main's preamble can
// reduce each column as contiguous float4 loads.
__global__ __launch_bounds__(256) void sums_kernel(
    const float* __restrict__ seeds, const float* __restrict__ es,
    const float* __restrict__ en, float* __restrict__ part,
    float* __restrict__ out, int V, int rows_per_block, int gsr_off) {
  __shared__ float sh[192];
  int t = threadIdx.x, bx = blockIdx.x;
  if (bx < 16) out[(bx << 8) + t] = 0.f;               // temp_exp_m accum
  else if (bx == 16 && t < 65) out[gsr_off + t] = 0.f; // gsr + qz
  if (t < 192) sh[t] = 0.f;
  __syncthreads();
  int k = t & 63, w = t >> 6;
  int v0 = bx * rows_per_block;
  int v1 = min(v0 + rows_per_block, V);
  float s0 = 0.f, s1 = 0.f, s2 = 0.f;
  for (int v = v0 + w; v < v1; v += 4) {
    int idx = (v << 6) + k;
    s0 += seeds[idx]; s1 += es[idx]; s2 += en[idx];
  }
  atomicAdd(&sh[k], s0);
  atomicAdd(&sh[64 + k], s1);
  atomicAdd(&sh[128 + k], s2);
  __syncthreads();
  if (t < 192) part[t * 256 + bx] = sh[t];   // column-major
}

// ---------- kernel B: persistent main — 2 blocks/CU, atomic epilogue ----
// R6: __launch_bounds__(1024,8) -> VGPR cap 64 (measured use 48), LDS
// 67.6KB x2 = 135KB <= 160KB, so TWO blocks co-reside per CU. Main is
// barrier/latency-bound (R4 counters: VALUBusy 4%, HBM 2%); the second
// block's waves issue while the first sits at __syncthreads.
__global__ __launch_bounds__(1024, 8) void main_kernel(
    const float* __restrict__ bow,   // (B=64, V)
    const float* __restrict__ seeds, // (V, 64)
    const float* __restrict__ exp_m, // (64, 64)
    const float* __restrict__ exp_s, // (V, 64)
    const float* __restrict__ exp_n, // (V, 64)
    const float* __restrict__ pi,    // (64)
    const float* __restrict__ part,  // 192 x 256 column-major partials
    float* __restrict__ out,
    int V, int gsr_off, int NB) {
  __shared__ short THbf[4096];     // bf16 th  [b][k]        swizzled   8 KB
  __shared__ short THTbf[4096];    // bf16 th^T [k][b]       swizzled   8 KB
  __shared__ short TLbf[4096];     // bf16 th*lnth [b][k]    swizzled   8 KB
  __shared__ short ARRT[1024];     // bf16 arr^T [v][k]      swizzled   2 KB
  __shared__ short ASVT[1024];     // bf16 (ass+asr)^T       swizzled   2 KB
  __shared__ short ARLT[1024];     // bf16 arr*ln(arr)^T     swizzled   2 KB
  __shared__ short WSRT[4096];     // bf16 [k][ws16|wr16]    swizzled   8 KB
  __shared__ short PKA[4096];      // bf16 [b][cis16|cir16]  swizzled   8 KB
  __shared__ short CIRT[1024];     // bf16 cirr^T [v][b]     swizzled   2 KB
  __shared__ float RSL[64 * 17];   // r_sum [b][v]  (alias NNL)      4.25 KB
  __shared__ float SSL[64 * 17];   // s_sum [b][v]  (alias red_gsr)  4.25 KB
  __shared__ float L0a[64 * 17];   // th*arrl part  (alias redq)     4.25 KB
  __shared__ float L0b[64 * 17];   // tl*arr  part                   4.25 KB
  __shared__ float sums_sh[192];
  float* NNL = RSL;
  float* red_gsr = SSL;
  float* redq = L0a;

  int t = threadIdx.x;
  int lane = t & 63, w = t >> 6;

  // ---- prefetch all this block's tile inputs (L2/L3-warm after sums) ----
  int gd = (int)gridDim.x;
  float sd[3], esv[3], env[3], bwv[3];
  int nt = 0;
#pragma unroll
  for (int i = 0; i < 3; i++) {
    int tile = (int)blockIdx.x + i * gd;
    if (tile < NB) {
      nt = i + 1;
      int v = (tile << 4) + w;
      if (v < V) {
        int rbase = (v << 6) + lane;
        sd[i]  = seeds[rbase];
        esv[i] = exp_s[rbase];
        env[i] = exp_n[rbase];
        bwv[i] = bow[lane * V + v];   // lane = b (cold gather, hidden here)
      } else {
        sd[i] = 0.f; esv[i] = 0.f; env[i] = 0.f; bwv[i] = 0.f;
      }
    }
  }
  float pik = pi[lane];
  float omp = 1.0f - pik;

  // ---- preamble ----
#pragma unroll
  for (int i = 0; i < 4; i++) {
    int idx = t + (i << 10);
    int b = idx >> 6, k = idx & 63;
    float th = exp_m[idx] + ETA_C;
    float lth = __logf(th);
    THbf[swz(b, k)] = bf16r(th);
    THTbf[swz(k, b)] = bf16r(th);
    TLbf[swz(b, k)] = bf16r(th * lth);
  }
  if (t < 192) sums_sh[t] = 0.f;
  __syncthreads();
  if (t < 768) {
    int col = t % 192;       // column of the partial matrix
    int seg = t / 192;       // 4 segments x 64 rows, contiguous float4s
    const f32x4* p = (const f32x4*)&part[col * 256 + (seg << 6)];
    float s = 0.f;
#pragma unroll
    for (int j = 0; j < 16; j++) {
      f32x4 v4 = p[j];
      s += (v4[0] + v4[1]) + (v4[2] + v4[3]);
    }
    atomicAdd(&sums_sh[col], s);
  }
  __syncthreads();

  int q = lane >> 4, c = lane & 15;
  float acc_g_tot = 0.f, acc_q_tot = 0.f;
  f32x4 accP = {0.f, 0.f, 0.f, 0.f};   // temp_exp_m tile, carried across tiles

#pragma unroll
  for (int it = 0; it < 3; it++) {
    if (it >= nt) break;
    int tile = (int)blockIdx.x + it * gd;
    int v = (tile << 4) + w;
    bool active = (v < V);

    // ---- phase A: per-v coefficient vectors (lane = k) ----
    float a_ss = 0.f, a_sr = 0.f, a_rr = 0.f;
    float bowpre = bwv[it];
    bool seedRow = false;
    if (active) {
      float seed = sd[it];
      float es = esv[it];
      float en = env[it];
      float inv_ds = __builtin_amdgcn_rcpf(MU_C * sums_sh[lane] + sums_sh[64 + lane]);
      float inv_dn = __builtin_amdgcn_rcpf(BETA_C * (float)V + sums_sh[128 + lane]);
      float phi_s = (MU_C + es) * inv_ds;
      float phi_n = (BETA_C + en) * inv_dn;
      a_ss = seed * phi_s * pik;
      a_sr = seed * phi_n * omp;
      a_rr = (1.0f - seed) * phi_n;
      seedRow = (__ballot(seed > 0.f) != 0ull);
      float wsv = fmaf(pik, a_ss, omp * a_sr);
      float wrv = seedRow ? omp * a_rr : a_rr;
      float arrl = (a_rr > 0.f) ? a_rr * __logf(a_rr) : 0.f;
      ARRT[swz(w, lane)] = bf16r(a_rr);
      ASVT[swz(w, lane)] = bf16r(a_ss + a_sr);
      ARLT[swz(w, lane)] = bf16r(arrl);
      WSRT[swz(lane, w)] = bf16r(wsv);
      WSRT[swz(lane, 16 + w)] = bf16r(wrv);
    } else {
      ARRT[swz(w, lane)] = 0;
      ASVT[swz(w, lane)] = 0;
      ARLT[swz(w, lane)] = 0;
      WSRT[swz(lane, w)] = 0;
      WSRT[swz(lane, 16 + w)] = 0;
    }
    __syncthreads();

    // ---- phase B: RS / SS / L0a / L0b MFMA matmuls ----
    {
      int job = w >> 2, mt = w & 3;
      const short* Amat = (job == 3) ? TLbf : THbf;
      const short* Bmat = (job == 0) ? ARRT : (job == 1) ? ASVT
                         : (job == 2) ? ARLT : ARRT;
      float* Cd = (job == 0) ? RSL : (job == 1) ? SSL : (job == 2) ? L0a : L0b;
      f32x4 acc = {0.f, 0.f, 0.f, 0.f};
      int arow = (mt << 4) + c;
#pragma unroll
      for (int s = 0; s < 2; s++) {
        short8 af = *(const short8*)&Amat[swz8(arow, (s << 2) + q)];
        short8 bf = *(const short8*)&Bmat[swz8(c, (s << 2) + q)];
        acc = __builtin_amdgcn_mfma_f32_16x16x32_bf16(af, bf, acc, 0, 0, 0);
      }
#pragma unroll
      for (int r = 0; r < 4; r++)
        Cd[((mt << 4) + (q << 2) + r) * 17 + c] = acc[r];
    }
    __syncthreads();

    // ---- phase C: per-v normalization (lane = b) + seed exact path ----
    float acc_s = 0.f, acc_g = 0.f, acc_qk = 0.f, acc_qb = 0.f;
    if (active) {
      float rsv = RSL[lane * 17 + w];
      float ssv = SSL[lane * 17 + w];
      float ivx = __builtin_amdgcn_rcpf(ssv + MINI_C);
      float ivy = __builtin_amdgcn_rcpf(rsv + MINI_C);
      float cis = bowpre * ivx;
      float cirr = bowpre * ivy;
      PKA[swz(lane, w)] = bf16r(cis);
      PKA[swz(lane, 16 + w)] = bf16r(cirr);
      CIRT[swz(w, lane)] = bf16r(cirr);
      if (!seedRow) {
        float Lb = L0a[lane * 17 + w] + L0b[lane * 17 + w];
        float q0 = (bowpre > 0.f) ? ivy : 0.f;
        float q1 = q0 * __logf(ivy);
        acc_qb = fmaf(q0, Lb, q1 * rsv);
        out[4096 + V * 64 + (v << 6) + lane] = 0.f;   // temp_exp_s
      } else {
        float acc_n = 0.f;
        unsigned long long m = __ballot(bowpre > 0.f);
        while (m) {
          int b = __builtin_amdgcn_readfirstlane(__builtin_ctzll(m));
          m &= (m - 1);
          float cb = rl(bowpre, b);
          float is = rl(ivx, b), ir = rl(ivy, b);
          float th = bf2f(THbf[swz(b, lane)]);
          float gss = th * a_ss * is;
          float gsr = th * a_sr * is;
          float grr = th * a_rr * ir;
          float gnr = gsr + grr;
          float gamma = fmaf(pik, gss, omp * gnr);
          acc_n = fmaf(gnr, cb, acc_n);
          acc_s = fmaf(gss, cb, acc_s);
          acc_g += gsr;
          acc_qk = fmaf(gamma, __logf(gamma + MINI_C), acc_qk);
        }
        out[4096 + (v << 6) + lane] = acc_n;
        out[4096 + V * 64 + (v << 6) + lane] = acc_s;
      }
    } else {
      PKA[swz(lane, w)] = 0;
      PKA[swz(lane, 16 + w)] = 0;
      CIRT[swz(w, lane)] = 0;
    }
    acc_g_tot += acc_g;
    acc_q_tot += acc_qk + acc_qb;
    __syncthreads();

    // ---- phase D: P matmul K-accumulated into accP + N matmul (w 12-15) ----
    {
      int tm = w >> 2, tn = w & 3;
      short8 af = *(const short8*)&PKA[swz8((tm << 4) + c, q)];
      short8 bf = *(const short8*)&WSRT[swz8((tn << 4) + c, q)];
      accP = __builtin_amdgcn_mfma_f32_16x16x32_bf16(af, bf, accP, 0, 0, 0);
      if (w >= 12) {
        int mt = w - 12;
        f32x4 an = {0.f, 0.f, 0.f, 0.f};
#pragma unroll
        for (int s = 0; s < 2; s++) {
          short8 a2 = *(const short8*)&THTbf[swz8((mt << 4) + c, (s << 2) + q)];
          short8 b2 = *(const short8*)&CIRT[swz8(c, (s << 2) + q)];
          an = __builtin_amdgcn_mfma_f32_16x16x32_bf16(a2, b2, an, 0, 0, 0);
        }
#pragma unroll
        for (int r = 0; r < 4; r++)
          NNL[((mt << 4) + (q << 2) + r) * 17 + c] = an[r];
      }
    }
    __syncthreads();

    // ---- phase E: temp_exp_n for non-seed rows (lane = k) ----
    if (active && !seedRow)
      out[4096 + (v << 6) + lane] = a_rr * NNL[lane * 17 + w];
  }

  // ---- epilogue: finalize temp_exp_m / gsr / qz with device atomics ----
  // (memory-side fp32 atomics across 256 lines; measured faster than a
  //  staged-store + finalize-kernel scheme, R2 post-mortem; cooperative
  //  grid.sync fusion measured at +100us, R4 post-mortem)
  {
    int tm = w >> 2, tn = w & 3;
#pragma unroll
    for (int r = 0; r < 4; r++) {
      int brow = (tm << 4) + (q << 2) + r;
      int kcol = (tn << 4) + c;
      float val = accP[r] * bf2f(THbf[swz(brow, kcol)]);
      atomicAdd(&out[(brow << 6) + kcol], val);
    }
  }
  __syncthreads();   // tiles done; SSL/L0a free for epilogue aliases
  red_gsr[t] = acc_g_tot;
  float qzw = wave_sum(acc_q_tot);
  if (lane == 0) redq[w] = qzw;
  __syncthreads();

  if (w == 0) {
    float g = 0.f;
#pragma unroll
    for (int j = 0; j < 16; j++) g += red_gsr[(j << 6) + lane];
    if (g != 0.f) atomicAdd(&out[gsr_off + lane], g);   // most blocks skip
    if (t == 0) {
      float qs = 0.f;
#pragma unroll
      for (int j = 0; j < 16; j++) qs += redq[j];
      atomicAdd(&out[gsr_off + 64], qs);
    }
  }
}

extern "C" void kernel_launch(void* const* d_in, const int* in_sizes, int n_in,
                              void* d_out, int out_size, void* d_ws,
                              size_t ws_size, hipStream_t stream) {
  (void)n_in; (void)out_size; (void)ws_size;
  const float* bow   = (const float*)d_in[0];
  const float* seeds = (const float*)d_in[1];
  const float* exp_m = (const float*)d_in[2];
  const float* exp_s = (const float*)d_in[3];
  const float* exp_n = (const float*)d_in[4];
  const float* pi    = (const float*)d_in[5];
  int K = in_sizes[5];          // 64
  int V = in_sizes[1] / K;      // 10000
  float* out = (float*)d_out;
  float* part = (float*)d_ws;   // 192 x 256 floats (column-major partials)

  int NB = (V + 15) / 16;       // 625 tiles of 16 v
  int NP = NB < 512 ? NB : 512; // persistent: TWO blocks per CU (R6)
  int gsr_off = 4096 + 2 * V * 64;
  int rpb = (V + 255) / 256;    // 40 rows per sums block

  sums_kernel<<<256, 256, 0, stream>>>(seeds, exp_s, exp_n, part, out, V, rpb,
                                       gsr_off);
  main_kernel<<<NP, 1024, 0, stream>>>(bow, seeds, exp_m, exp_s, exp_n, pi,
                                       part, out, V, gsr_off, NB);
}

// Round 7
// 101.961 us; speedup vs baseline: 1.1048x; 1.1048x over previous
//
#include <hip/hip_runtime.h>
#include <hip/hip_bf16.h>

#define ETA_C  0.1f
#define BETA_C 0.05f
#define MU_C   0.05f
#define MINI_C 1e-6f

typedef __attribute__((ext_vector_type(8))) short short8;
typedef __attribute__((ext_vector_type(4))) float f32x4;

// ---------- DPP wave-64 sum ----------
template<int CTRL, int ROWMASK>
__device__ __forceinline__ float dpp_add(float x) {
  int v = __builtin_amdgcn_update_dpp(0, __float_as_int(x), CTRL, ROWMASK, 0xf, true);
  return x + __int_as_float(v);
}

__device__ __forceinline__ float wave_sum(float x) {
  x = dpp_add<0xB1,  0xF>(x);
  x = dpp_add<0x4E,  0xF>(x);
  x = dpp_add<0x141, 0xF>(x);
  x = dpp_add<0x140, 0xF>(x);
  x = dpp_add<0x142, 0xA>(x);
  x = dpp_add<0x143, 0xC>(x);
  return __int_as_float(__builtin_amdgcn_readlane(__float_as_int(x), 63));
}

__device__ __forceinline__ float rl(float x, int k) {
  return __int_as_float(__builtin_amdgcn_readlane(__float_as_int(x), k));
}

__device__ __forceinline__ short bf16r(float x) {
  unsigned u = __float_as_uint(x);
  u += 0x7fffu + ((u >> 16) & 1u);
  return (short)(u >> 16);
}

__device__ __forceinline__ float bf2f(short s) {
  return __uint_as_float(((unsigned)(unsigned short)s) << 16);
}

// ---------- LDS XOR swizzle for 64-short (128B) rows ----------
// Column-slice reads of row-major [*][64] bf16 tiles are 16-way bank
// conflicts (row stride 128B == 32 banks). XOR the 16B slot with (row&7):
// reads (short8) drop to 2-way (free), column writes to <=8-way.
// R4->R5: SQ_LDS_BANK_CONFLICT 3.0M -> gone, -2 us.
__device__ __forceinline__ int swz(int row, int col) {
  return (row << 6) + ((col & 7) | ((((col >> 3) ^ row) & 7) << 3));
}
__device__ __forceinline__ int swz8(int row, int slot) {   // 16B-aligned slot
  return (row << 6) + (((slot ^ row) & 7) << 3);
}

// ---------- kernel A: per-block column-sum partials + zero atomic dests ----
// 256 blocks (1/CU): full-chip streaming of the 7.7 MB cold input.
// part written COLUMN-major (part[col*256 + bx]) so main's preamble can
// reduce each column as contiguous float4 loads.
__global__ __launch_bounds__(256) void sums_kernel(
    const float* __restrict__ seeds, const float* __restrict__ es,
    const float* __restrict__ en, float* __restrict__ part,
    float* __restrict__ out, int V, int rows_per_block, int gsr_off) {
  __shared__ float sh[192];
  int t = threadIdx.x, bx = blockIdx.x;
  if (bx < 16) out[(bx << 8) + t] = 0.f;               // temp_exp_m accum
  else if (bx == 16 && t < 65) out[gsr_off + t] = 0.f; // gsr + qz
  if (t < 192) sh[t] = 0.f;
  __syncthreads();
  int k = t & 63, w = t >> 6;
  int v0 = bx * rows_per_block;
  int v1 = min(v0 + rows_per_block, V);
  float s0 = 0.f, s1 = 0.f, s2 = 0.f;
  for (int v = v0 + w; v < v1; v += 4) {
    int idx = (v << 6) + k;
    s0 += seeds[idx]; s1 += es[idx]; s2 += en[idx];
  }
  atomicAdd(&sh[k], s0);
  atomicAdd(&sh[64 + k], s1);
  atomicAdd(&sh[128 + k], s2);
  __syncthreads();
  if (t < 192) part[t * 256 + bx] = sh[t];   // column-major
}

// ---------- kernel B: persistent main — 1 block/CU, atomic epilogue ----
// R6 post-mortem: 2 blocks/CU (launch_bounds(1024,8), NP=512) was +9.6us —
// VGPR cap 64 constrains regalloc, preamble work doubles chip-wide. Keep
// ONE block/CU (cap 128, measured use 48) as in R5.
// R7: heavy tiles (v<640 contain seed rows -> serial readlane loop in
// phase C) are remapped +512 mod NB so each lands on a distinct 2-tile
// block (113..152) instead of stacking onto 3-tile blocks 0..39.
__global__ __launch_bounds__(1024, 4) void main_kernel(
    const float* __restrict__ bow,   // (B=64, V)
    const float* __restrict__ seeds, // (V, 64)
    const float* __restrict__ exp_m, // (64, 64)
    const float* __restrict__ exp_s, // (V, 64)
    const float* __restrict__ exp_n, // (V, 64)
    const float* __restrict__ pi,    // (64)
    const float* __restrict__ part,  // 192 x 256 column-major partials
    float* __restrict__ out,
    int V, int gsr_off, int NB, int toff) {
  __shared__ short THbf[4096];     // bf16 th  [b][k]        swizzled   8 KB
  __shared__ short THTbf[4096];    // bf16 th^T [k][b]       swizzled   8 KB
  __shared__ short TLbf[4096];     // bf16 th*lnth [b][k]    swizzled   8 KB
  __shared__ short ARRT[1024];     // bf16 arr^T [v][k]      swizzled   2 KB
  __shared__ short ASVT[1024];     // bf16 (ass+asr)^T       swizzled   2 KB
  __shared__ short ARLT[1024];     // bf16 arr*ln(arr)^T     swizzled   2 KB
  __shared__ short WSRT[4096];     // bf16 [k][ws16|wr16]    swizzled   8 KB
  __shared__ short PKA[4096];      // bf16 [b][cis16|cir16]  swizzled   8 KB
  __shared__ short CIRT[1024];     // bf16 cirr^T [v][b]     swizzled   2 KB
  __shared__ float RSL[64 * 17];   // r_sum [b][v]  (alias NNL)      4.25 KB
  __shared__ float SSL[64 * 17];   // s_sum [b][v]  (alias red_gsr)  4.25 KB
  __shared__ float L0a[64 * 17];   // th*arrl part  (alias redq)     4.25 KB
  __shared__ float L0b[64 * 17];   // tl*arr  part                   4.25 KB
  __shared__ float sums_sh[192];
  float* NNL = RSL;
  float* red_gsr = SSL;
  float* redq = L0a;

  int t = threadIdx.x;
  int lane = t & 63, w = t >> 6;

  // ---- prefetch all this block's tile inputs (L2/L3-warm after sums) ----
  int gd = (int)gridDim.x;
  float sd[3], esv[3], env[3], bwv[3];
  int nt = 0;
#pragma unroll
  for (int i = 0; i < 3; i++) {
    int vt = (int)blockIdx.x + i * gd;
    if (vt < NB) {
      nt = i + 1;
      int tile = vt + toff; if (tile >= NB) tile -= NB;   // heavy-tile remap
      int v = (tile << 4) + w;
      if (v < V) {
        int rbase = (v << 6) + lane;
        sd[i]  = seeds[rbase];
        esv[i] = exp_s[rbase];
        env[i] = exp_n[rbase];
        bwv[i] = bow[lane * V + v];   // lane = b (cold gather, hidden here)
      } else {
        sd[i] = 0.f; esv[i] = 0.f; env[i] = 0.f; bwv[i] = 0.f;
      }
    }
  }
  float pik = pi[lane];
  float omp = 1.0f - pik;

  // ---- preamble: once per CU ----
#pragma unroll
  for (int i = 0; i < 4; i++) {
    int idx = t + (i << 10);
    int b = idx >> 6, k = idx & 63;
    float th = exp_m[idx] + ETA_C;
    float lth = __logf(th);
    THbf[swz(b, k)] = bf16r(th);
    THTbf[swz(k, b)] = bf16r(th);
    TLbf[swz(b, k)] = bf16r(th * lth);
  }
  if (t < 192) sums_sh[t] = 0.f;
  __syncthreads();
  if (t < 768) {
    int col = t % 192;       // column of the partial matrix
    int seg = t / 192;       // 4 segments x 64 rows, contiguous float4s
    const f32x4* p = (const f32x4*)&part[col * 256 + (seg << 6)];
    float s = 0.f;
#pragma unroll
    for (int j = 0; j < 16; j++) {
      f32x4 v4 = p[j];
      s += (v4[0] + v4[1]) + (v4[2] + v4[3]);
    }
    atomicAdd(&sums_sh[col], s);
  }
  __syncthreads();

  int q = lane >> 4, c = lane & 15;
  float acc_g_tot = 0.f, acc_q_tot = 0.f;
  f32x4 accP = {0.f, 0.f, 0.f, 0.f};   // temp_exp_m tile, carried across tiles

#pragma unroll
  for (int it = 0; it < 3; it++) {
    if (it >= nt) break;
    int vt = (int)blockIdx.x + it * gd;
    int tile = vt + toff; if (tile >= NB) tile -= NB;     // heavy-tile remap
    int v = (tile << 4) + w;
    bool active = (v < V);

    // ---- phase A: per-v coefficient vectors (lane = k) ----
    float a_ss = 0.f, a_sr = 0.f, a_rr = 0.f;
    float bowpre = bwv[it];
    bool seedRow = false;
    if (active) {
      float seed = sd[it];
      float es = esv[it];
      float en = env[it];
      float inv_ds = __builtin_amdgcn_rcpf(MU_C * sums_sh[lane] + sums_sh[64 + lane]);
      float inv_dn = __builtin_amdgcn_rcpf(BETA_C * (float)V + sums_sh[128 + lane]);
      float phi_s = (MU_C + es) * inv_ds;
      float phi_n = (BETA_C + en) * inv_dn;
      a_ss = seed * phi_s * pik;
      a_sr = seed * phi_n * omp;
      a_rr = (1.0f - seed) * phi_n;
      seedRow = (__ballot(seed > 0.f) != 0ull);
      float wsv = fmaf(pik, a_ss, omp * a_sr);
      float wrv = seedRow ? omp * a_rr : a_rr;
      float arrl = (a_rr > 0.f) ? a_rr * __logf(a_rr) : 0.f;
      ARRT[swz(w, lane)] = bf16r(a_rr);
      ASVT[swz(w, lane)] = bf16r(a_ss + a_sr);
      ARLT[swz(w, lane)] = bf16r(arrl);
      WSRT[swz(lane, w)] = bf16r(wsv);
      WSRT[swz(lane, 16 + w)] = bf16r(wrv);
    } else {
      ARRT[swz(w, lane)] = 0;
      ASVT[swz(w, lane)] = 0;
      ARLT[swz(w, lane)] = 0;
      WSRT[swz(lane, w)] = 0;
      WSRT[swz(lane, 16 + w)] = 0;
    }
    __syncthreads();

    // ---- phase B: RS / SS / L0a / L0b MFMA matmuls ----
    {
      int job = w >> 2, mt = w & 3;
      const short* Amat = (job == 3) ? TLbf : THbf;
      const short* Bmat = (job == 0) ? ARRT : (job == 1) ? ASVT
                         : (job == 2) ? ARLT : ARRT;
      float* Cd = (job == 0) ? RSL : (job == 1) ? SSL : (job == 2) ? L0a : L0b;
      f32x4 acc = {0.f, 0.f, 0.f, 0.f};
      int arow = (mt << 4) + c;
#pragma unroll
      for (int s = 0; s < 2; s++) {
        short8 af = *(const short8*)&Amat[swz8(arow, (s << 2) + q)];
        short8 bf = *(const short8*)&Bmat[swz8(c, (s << 2) + q)];
        acc = __builtin_amdgcn_mfma_f32_16x16x32_bf16(af, bf, acc, 0, 0, 0);
      }
#pragma unroll
      for (int r = 0; r < 4; r++)
        Cd[((mt << 4) + (q << 2) + r) * 17 + c] = acc[r];
    }
    __syncthreads();

    // ---- phase C: per-v normalization (lane = b) + seed exact path ----
    float acc_s = 0.f, acc_g = 0.f, acc_qk = 0.f, acc_qb = 0.f;
    if (active) {
      float rsv = RSL[lane * 17 + w];
      float ssv = SSL[lane * 17 + w];
      float ivx = __builtin_amdgcn_rcpf(ssv + MINI_C);
      float ivy = __builtin_amdgcn_rcpf(rsv + MINI_C);
      float cis = bowpre * ivx;
      float cirr = bowpre * ivy;
      PKA[swz(lane, w)] = bf16r(cis);
      PKA[swz(lane, 16 + w)] = bf16r(cirr);
      CIRT[swz(w, lane)] = bf16r(cirr);
      if (!seedRow) {
        float Lb = L0a[lane * 17 + w] + L0b[lane * 17 + w];
        float q0 = (bowpre > 0.f) ? ivy : 0.f;
        float q1 = q0 * __logf(ivy);
        acc_qb = fmaf(q0, Lb, q1 * rsv);
        out[4096 + V * 64 + (v << 6) + lane] = 0.f;   // temp_exp_s
      } else {
        float acc_n = 0.f;
        unsigned long long m = __ballot(bowpre > 0.f);
        while (m) {
          int b = __builtin_amdgcn_readfirstlane(__builtin_ctzll(m));
          m &= (m - 1);
          float cb = rl(bowpre, b);
          float is = rl(ivx, b), ir = rl(ivy, b);
          float th = bf2f(THbf[swz(b, lane)]);
          float gss = th * a_ss * is;
          float gsr = th * a_sr * is;
          float grr = th * a_rr * ir;
          float gnr = gsr + grr;
          float gamma = fmaf(pik, gss, omp * gnr);
          acc_n = fmaf(gnr, cb, acc_n);
          acc_s = fmaf(gss, cb, acc_s);
          acc_g += gsr;
          acc_qk = fmaf(gamma, __logf(gamma + MINI_C), acc_qk);
        }
        out[4096 + (v << 6) + lane] = acc_n;
        out[4096 + V * 64 + (v << 6) + lane] = acc_s;
      }
    } else {
      PKA[swz(lane, w)] = 0;
      PKA[swz(lane, 16 + w)] = 0;
      CIRT[swz(w, lane)] = 0;
    }
    acc_g_tot += acc_g;
    acc_q_tot += acc_qk + acc_qb;
    __syncthreads();

    // ---- phase D: P matmul K-accumulated into accP + N matmul (w 12-15) ----
    {
      int tm = w >> 2, tn = w & 3;
      short8 af = *(const short8*)&PKA[swz8((tm << 4) + c, q)];
      short8 bf = *(const short8*)&WSRT[swz8((tn << 4) + c, q)];
      accP = __builtin_amdgcn_mfma_f32_16x16x32_bf16(af, bf, accP, 0, 0, 0);
      if (w >= 12) {
        int mt = w - 12;
        f32x4 an = {0.f, 0.f, 0.f, 0.f};
#pragma unroll
        for (int s = 0; s < 2; s++) {
          short8 a2 = *(const short8*)&THTbf[swz8((mt << 4) + c, (s << 2) + q)];
          short8 b2 = *(const short8*)&CIRT[swz8(c, (s << 2) + q)];
          an = __builtin_amdgcn_mfma_f32_16x16x32_bf16(a2, b2, an, 0, 0, 0);
        }
#pragma unroll
        for (int r = 0; r < 4; r++)
          NNL[((mt << 4) + (q << 2) + r) * 17 + c] = an[r];
      }
    }
    __syncthreads();

    // ---- phase E: temp_exp_n for non-seed rows (lane = k) ----
    if (active && !seedRow)
      out[4096 + (v << 6) + lane] = a_rr * NNL[lane * 17 + w];
  }

  // ---- epilogue: finalize temp_exp_m / gsr / qz with device atomics ----
  // (memory-side fp32 atomics across 256 lines; measured faster than a
  //  staged-store + finalize-kernel scheme, R2 post-mortem; cooperative
  //  grid.sync fusion measured at +100us, R4 post-mortem)
  {
    int tm = w >> 2, tn = w & 3;
#pragma unroll
    for (int r = 0; r < 4; r++) {
      int brow = (tm << 4) + (q << 2) + r;
      int kcol = (tn << 4) + c;
      float val = accP[r] * bf2f(THbf[swz(brow, kcol)]);
      atomicAdd(&out[(brow << 6) + kcol], val);
    }
  }
  __syncthreads();   // tiles done; SSL/L0a free for epilogue aliases
  red_gsr[t] = acc_g_tot;
  float qzw = wave_sum(acc_q_tot);
  if (lane == 0) redq[w] = qzw;
  __syncthreads();

  if (w == 0) {
    float g = 0.f;
#pragma unroll
    for (int j = 0; j < 16; j++) g += red_gsr[(j << 6) + lane];
    if (g != 0.f) atomicAdd(&out[gsr_off + lane], g);   // most blocks skip
    if (t == 0) {
      float qs = 0.f;
#pragma unroll
      for (int j = 0; j < 16; j++) qs += redq[j];
      atomicAdd(&out[gsr_off + 64], qs);
    }
  }
}

extern "C" void kernel_launch(void* const* d_in, const int* in_sizes, int n_in,
                              void* d_out, int out_size, void* d_ws,
                              size_t ws_size, hipStream_t stream) {
  (void)n_in; (void)out_size; (void)ws_size;
  const float* bow   = (const float*)d_in[0];
  const float* seeds = (const float*)d_in[1];
  const float* exp_m = (const float*)d_in[2];
  const float* exp_s = (const float*)d_in[3];
  const float* exp_n = (const float*)d_in[4];
  const float* pi    = (const float*)d_in[5];
  int K = in_sizes[5];          // 64
  int V = in_sizes[1] / K;      // 10000
  float* out = (float*)d_out;
  float* part = (float*)d_ws;   // 192 x 256 floats (column-major partials)

  int NB = (V + 15) / 16;       // 625 tiles of 16 v
  int NP = NB < 256 ? NB : 256; // persistent: one block per CU (R5 config)
  int gsr_off = 4096 + 2 * V * 64;
  int rpb = (V + 255) / 256;    // 40 rows per sums block
  int toff = (NB > 512) ? 512 : 0;  // heavy tiles -> 2-tile blocks (R7)

  sums_kernel<<<256, 256, 0, stream>>>(seeds, exp_s, exp_n, part, out, V, rpb,
                                       gsr_off);
  main_kernel<<<NP, 1024, 0, stream>>>(bow, seeds, exp_m, exp_s, exp_n, pi,
                                       part, out, V, gsr_off, NB, toff);
}